// Round 1
// baseline (10698.433 us; speedup 1.0000x reference)
//
#include <hip/hip_runtime.h>

#define Bsz 32
#define Lsz 128
#define Csz 192
#define TL 16
#define NTHR 384

__device__ __forceinline__ float sigmoid_f(float x) {
    return 1.0f / (1.0f + __expf(-x));
}

// Accurate-for-small-x tanh: poly below 1/16 (abs err ~2e-10), exp form above
// (abs err ~1e-7 but only hit mid-trajectory where it decays before output).
__device__ __forceinline__ float tanh_f(float x) {
    float ax = fabsf(x);
    if (ax < 0.0625f) {
        float x2 = x * x;
        return x * fmaf(x2, fmaf(x2, 0.13333333f, -0.33333333f), 1.0f);
    }
    float e = __expf(2.0f * fminf(ax, 20.0f));
    float t = (e - 1.0f) / (e + 1.0f);
    return x < 0.0f ? -t : t;
}

// K1: gate = sigmoid(conv_g(mem)+bg); rm = sigmoid(conv_r(mem)+br) * mem
__global__ __launch_bounds__(NTHR)
void dngpu_k1(const float* __restrict__ mem,
              const float* __restrict__ w_r, const float* __restrict__ b_r,
              const float* __restrict__ w_g, const float* __restrict__ b_g,
              float* __restrict__ gateb, float* __restrict__ rmb)
{
    __shared__ float lds[Csz * 20];           // transposed [ci][row], row = l - base
    const int tid  = threadIdx.x;
    const int b    = blockIdx.y;
    const int tile = blockIdx.x;
    const int base = tile * TL - 1;           // global l of lds row 0
    const float* memb = mem + (size_t)b * Lsz * Csz;

    for (int idx = tid; idx < 18 * Csz; idx += NTHR) {
        const int row = idx / Csz;
        const int ci  = idx - row * Csz;
        const int gl  = base + row;
        float v = 0.0f;
        if (gl >= 0 && gl < Lsz) v = memb[gl * Csz + ci];
        lds[ci * 20 + row] = v;
    }
    __syncthreads();

    const int cp = tid % 96;                  // c-pair id
    const int lh = tid / 96;                  // l-quad id, 0..3
    const int c0 = cp * 2;
    const int vb = lh * 4;

    float accr[4][2] = {};
    float accg[4][2] = {};

    const float* wr0 = w_r + c0;
    const float* wg0 = w_g + c0;

    for (int ci = 0; ci < Csz; ++ci) {
        float v[6];
        const float4 t0 = *reinterpret_cast<const float4*>(&lds[ci * 20 + vb]);
        const float2 t1 = *reinterpret_cast<const float2*>(&lds[ci * 20 + vb + 4]);
        v[0] = t0.x; v[1] = t0.y; v[2] = t0.z; v[3] = t0.w; v[4] = t1.x; v[5] = t1.y;
        #pragma unroll
        for (int kk = 0; kk < 3; ++kk) {
            const int wo = (kk * Csz + ci) * Csz;
            const float2 wr = *reinterpret_cast<const float2*>(&wr0[wo]);
            const float2 wg = *reinterpret_cast<const float2*>(&wg0[wo]);
            #pragma unroll
            for (int i = 0; i < 4; ++i) {
                accr[i][0] = fmaf(v[i + kk], wr.x, accr[i][0]);
                accr[i][1] = fmaf(v[i + kk], wr.y, accr[i][1]);
                accg[i][0] = fmaf(v[i + kk], wg.x, accg[i][0]);
                accg[i][1] = fmaf(v[i + kk], wg.y, accg[i][1]);
            }
        }
    }

    const float br0 = b_r[c0], br1 = b_r[c0 + 1];
    const float bg0 = b_g[c0], bg1 = b_g[c0 + 1];
    const int l0 = tile * TL + lh * 4;
    #pragma unroll
    for (int i = 0; i < 4; ++i) {
        const int l = l0 + i;
        const float2 mv = *reinterpret_cast<const float2*>(&memb[l * Csz + c0]);
        const float r0 = sigmoid_f(accr[i][0] + br0);
        const float r1 = sigmoid_f(accr[i][1] + br1);
        const float g0 = sigmoid_f(accg[i][0] + bg0);
        const float g1 = sigmoid_f(accg[i][1] + bg1);
        *reinterpret_cast<float2*>(&gateb[((size_t)b * Lsz + l) * Csz + c0]) = make_float2(g0, g1);
        *reinterpret_cast<float2*>(&rmb[((size_t)b * Lsz + l) * Csz + c0])   = make_float2(r0 * mv.x, r1 * mv.y);
    }
}

// K2: cand = tanh(conv_c(rm)+bc); out = gate*shift(mem) + (1-gate)*cand
__global__ __launch_bounds__(NTHR)
void dngpu_k2(const float* __restrict__ rmb,
              const float* __restrict__ w_c, const float* __restrict__ b_c,
              const float* __restrict__ gateb, const float* __restrict__ memin,
              float* __restrict__ memout)
{
    __shared__ float lds[Csz * 20];
    const int tid  = threadIdx.x;
    const int b    = blockIdx.y;
    const int tile = blockIdx.x;
    const int base = tile * TL - 1;
    const float* rmbb = rmb + (size_t)b * Lsz * Csz;

    for (int idx = tid; idx < 18 * Csz; idx += NTHR) {
        const int row = idx / Csz;
        const int ci  = idx - row * Csz;
        const int gl  = base + row;
        float v = 0.0f;
        if (gl >= 0 && gl < Lsz) v = rmbb[gl * Csz + ci];
        lds[ci * 20 + row] = v;
    }
    __syncthreads();

    const int cp = tid % 96;
    const int lh = tid / 96;
    const int c0 = cp * 2;
    const int vb = lh * 4;

    float acc[4][2] = {};
    const float* wc0 = w_c + c0;

    for (int ci = 0; ci < Csz; ++ci) {
        float v[6];
        const float4 t0 = *reinterpret_cast<const float4*>(&lds[ci * 20 + vb]);
        const float2 t1 = *reinterpret_cast<const float2*>(&lds[ci * 20 + vb + 4]);
        v[0] = t0.x; v[1] = t0.y; v[2] = t0.z; v[3] = t0.w; v[4] = t1.x; v[5] = t1.y;
        #pragma unroll
        for (int kk = 0; kk < 3; ++kk) {
            const float2 wc = *reinterpret_cast<const float2*>(&wc0[(kk * Csz + ci) * Csz]);
            #pragma unroll
            for (int i = 0; i < 4; ++i) {
                acc[i][0] = fmaf(v[i + kk], wc.x, acc[i][0]);
                acc[i][1] = fmaf(v[i + kk], wc.y, acc[i][1]);
            }
        }
    }

    const float bc0 = b_c[c0], bc1 = b_c[c0 + 1];
    const int l0 = tile * TL + lh * 4;
    const float* memb = memin + (size_t)b * Lsz * Csz;
    #pragma unroll
    for (int i = 0; i < 4; ++i) {
        const int l = l0 + i;
        const float cand0 = tanh_f(acc[i][0] + bc0);
        const float cand1 = tanh_f(acc[i][1] + bc1);
        const float2 gv = *reinterpret_cast<const float2*>(&gateb[((size_t)b * Lsz + l) * Csz + c0]);
        float2 sh = make_float2(0.0f, 0.0f);
        if (l > 0) sh = *reinterpret_cast<const float2*>(&memb[(l - 1) * Csz + c0]);
        const float o0 = gv.x * sh.x + (1.0f - gv.x) * cand0;
        const float o1 = gv.y * sh.y + (1.0f - gv.y) * cand1;
        *reinterpret_cast<float2*>(&memout[((size_t)b * Lsz + l) * Csz + c0]) = make_float2(o0, o1);
    }
}

extern "C" void kernel_launch(void* const* d_in, const int* in_sizes, int n_in,
                              void* d_out, int out_size, void* d_ws, size_t ws_size,
                              hipStream_t stream)
{
    (void)in_sizes; (void)n_in; (void)out_size; (void)ws_size;
    const float* x   = (const float*)d_in[0];
    const float* w_r = (const float*)d_in[1];
    const float* b_r = (const float*)d_in[2];
    const float* w_g = (const float*)d_in[3];
    const float* b_g = (const float*)d_in[4];
    const float* w_c = (const float*)d_in[5];
    const float* b_c = (const float*)d_in[6];
    float* out = (float*)d_out;

    const size_t N = (size_t)Bsz * Lsz * Csz;     // 786432 floats
    float* wsA  = (float*)d_ws;                   // mem ping buffer
    float* gate = wsA + N;
    float* rm   = gate + N;

    dim3 grid(Lsz / TL, Bsz);                     // (8, 32) = 256 blocks
    dim3 block(NTHR);

    const float* cur = x;
    for (int t = 0; t < 128; ++t) {
        float* nxt = (t & 1) ? out : wsA;         // t=127 (odd) -> d_out
        dngpu_k1<<<grid, block, 0, stream>>>(cur, w_r, b_r, w_g, b_g, gate, rm);
        dngpu_k2<<<grid, block, 0, stream>>>(rm, w_c, b_c, gate, cur, nxt);
        cur = nxt;
    }
}

// Round 2
// 3493.347 us; speedup vs baseline: 3.0625x; 3.0625x over previous
//
#include <hip/hip_runtime.h>

typedef __attribute__((ext_vector_type(8))) short short8;
typedef __attribute__((ext_vector_type(4))) float f32x4;

#define NROWS 4096     // B*L = 32*128
#define CC    192
#define NCEL  (NROWS * CC)

// ---------- numerics helpers ----------
__device__ __forceinline__ unsigned short f2bf(float x) {
    union { float f; unsigned int u; } v; v.f = x;
    unsigned int r = v.u + 0x7fffu + ((v.u >> 16) & 1u);   // RNE
    return (unsigned short)(r >> 16);
}
__device__ __forceinline__ float bf2f(unsigned short h) {
    union { unsigned int u; float f; } v; v.u = ((unsigned int)h) << 16;
    return v.f;
}
__device__ __forceinline__ void splitf(float x, unsigned short& h, unsigned short& l) {
    h = f2bf(x);
    l = f2bf(x - bf2f(h));
}
__device__ __forceinline__ float sigmoid_f(float x) {
    return 1.0f / (1.0f + __expf(-x));
}
// poly for small |x| (abs err ~2e-10), exp form above (err decays before output)
__device__ __forceinline__ float tanh_f(float x) {
    float ax = fabsf(x);
    if (ax < 0.0625f) {
        float x2 = x * x;
        return x * fmaf(x2, fmaf(x2, 0.13333333f, -0.33333333f), 1.0f);
    }
    float e = __expf(2.0f * fminf(ax, 20.0f));
    float t = (e - 1.0f) / (e + 1.0f);
    return x < 0.0f ? -t : t;
}

// ---------- prep kernels ----------
__global__ void prep_x(const float* __restrict__ x,
                       unsigned short* __restrict__ mh, unsigned short* __restrict__ ml) {
    int i = blockIdx.x * 256 + threadIdx.x;
    if (i < NCEL) { unsigned short h, l; splitf(x[i], h, l); mh[i] = h; ml[i] = l; }
}

// w layout [kk][ci][co] == [k][co]; output Wt[conv*192+co][k] (bf16 h/l)
__global__ void prep_w(const float* __restrict__ wr, const float* __restrict__ wg,
                       const float* __restrict__ wc,
                       unsigned short* __restrict__ WtH, unsigned short* __restrict__ WtL) {
    int i = blockIdx.x * 256 + threadIdx.x;
    if (i >= 3 * 576 * 192) return;
    int conv = i / (576 * 192);
    int rem  = i - conv * (576 * 192);
    int k  = rem / 192;
    int co = rem - k * 192;
    const float* w = (conv == 0) ? wr : ((conv == 1) ? wg : wc);
    float v = w[rem];
    size_t o = ((size_t)(conv * 192 + co)) * 576 + k;
    unsigned short h, l; splitf(v, h, l);
    WtH[o] = h; WtL[o] = l;
}

// ---------- GEMM kernels ----------
// tile 32 rows x 96 cols, 4 waves (2m x 2n), wave = 16x48 (m1 n3), K chunks of 32
// A tile: 34 rows (n0-1 .. n0+32), XOR-swizzled; W: per-chunk LDS, stride 40 ushorts, dbuf

__global__ __launch_bounds__(256, 2)
void k1_rg(const unsigned short* __restrict__ memH, const unsigned short* __restrict__ memL,
           const unsigned short* __restrict__ WtH, const unsigned short* __restrict__ WtL,
           const float* __restrict__ b_r, const float* __restrict__ b_g,
           float* __restrict__ gate, unsigned short* __restrict__ rmH,
           unsigned short* __restrict__ rmL)
{
    __shared__ __align__(16) unsigned short AH[34 * 192];
    __shared__ __align__(16) unsigned short AL[34 * 192];
    __shared__ __align__(16) unsigned short WB[2][2][96 * 40];

    const int mt = blockIdx.x;          // 0..127
    const int nt = blockIdx.y;          // 0..3 : 0,1 = reset ; 2,3 = gate
    const int conv  = nt >> 1;
    const int cbase = (nt & 1) * 96;
    const int n0  = mt * 32;
    const int tid = threadIdx.x;

    // ---- stage A (h+l), 16B units: 34 rows * 24/row * 2 = 1632
    #pragma unroll
    for (int it = 0; it < 7; ++it) {
        int q = it * 256 + tid;
        if (q < 34 * 24 * 2) {
            int hl = q >= 34 * 24;
            int qq = hl ? q - 34 * 24 : q;
            int tr = qq / 24;
            int cq = qq - tr * 24;
            int nr = n0 - 1 + tr;
            bool valid = (nr >= 0) && ((nr >> 7) == (n0 >> 7));
            uint4 v = make_uint4(0u, 0u, 0u, 0u);
            if (valid) {
                const unsigned short* src = (hl ? memL : memH) + (size_t)nr * 192 + cq * 8;
                v = *reinterpret_cast<const uint4*>(src);
            }
            unsigned int byt = ((unsigned)(cq * 16)) ^ (((unsigned)(tr & 7)) << 4);
            unsigned short* dst = (hl ? AL : AH) + tr * 192 + (byt >> 1);
            *reinterpret_cast<uint4*>(dst) = v;
        }
    }

    const unsigned short* WtHc = WtH + (size_t)(conv * 192 + cbase) * 576;
    const unsigned short* WtLc = WtL + (size_t)(conv * 192 + cbase) * 576;

    auto stageW = [&](int buf, int ch) {
        int k0 = ch * 32;
        #pragma unroll
        for (int it = 0; it < 3; ++it) {
            int q = it * 256 + tid;               // 96*4*2 = 768 = 3*256
            int hl = q >= 96 * 4;
            int qq = hl ? q - 96 * 4 : q;
            int cc = qq >> 2;
            int kq = (qq & 3) * 8;
            const unsigned short* src = (hl ? WtLc : WtHc) + (size_t)cc * 576 + k0 + kq;
            uint4 v = *reinterpret_cast<const uint4*>(src);
            *reinterpret_cast<uint4*>(&WB[buf][hl][cc * 40 + kq]) = v;
        }
    };

    const int lane = tid & 63;
    const int wave = tid >> 6;
    const int wm = wave & 1;
    const int wn = wave >> 1;
    const int lrow = lane & 15;
    const int lk = (lane >> 4) * 8;

    f32x4 acc[3] = { {0.f,0.f,0.f,0.f}, {0.f,0.f,0.f,0.f}, {0.f,0.f,0.f,0.f} };

    stageW(0, 0);
    __syncthreads();

    int buf = 0;
    #pragma unroll
    for (int kk = 0; kk < 3; ++kk) {
        #pragma unroll
        for (int cb = 0; cb < 6; ++cb) {
            const int ch = kk * 6 + cb;
            if (ch < 17) stageW(buf ^ 1, ch + 1);
            const int tr = 16 * wm + lrow + kk;
            const unsigned int abyt = ((unsigned)(cb * 64 + lk * 2)) ^ (((unsigned)(tr & 7)) << 4);
            const int aoff = tr * 192 + (abyt >> 1);
            short8 aH = *reinterpret_cast<const short8*>(&AH[aoff]);
            short8 aL = *reinterpret_cast<const short8*>(&AL[aoff]);
            const int c0 = 48 * wn + lrow;
            short8 bH[3], bL[3];
            #pragma unroll
            for (int j = 0; j < 3; ++j) {
                bH[j] = *reinterpret_cast<const short8*>(&WB[buf][0][(c0 + 16 * j) * 40 + lk]);
                bL[j] = *reinterpret_cast<const short8*>(&WB[buf][1][(c0 + 16 * j) * 40 + lk]);
            }
            #pragma unroll
            for (int j = 0; j < 3; ++j)
                acc[j] = __builtin_amdgcn_mfma_f32_16x16x32_bf16(aH, bH[j], acc[j], 0, 0, 0);
            #pragma unroll
            for (int j = 0; j < 3; ++j)
                acc[j] = __builtin_amdgcn_mfma_f32_16x16x32_bf16(aL, bH[j], acc[j], 0, 0, 0);
            #pragma unroll
            for (int j = 0; j < 3; ++j)
                acc[j] = __builtin_amdgcn_mfma_f32_16x16x32_bf16(aH, bL[j], acc[j], 0, 0, 0);
            __syncthreads();
            buf ^= 1;
        }
    }

    // ---- epilogue
    #pragma unroll
    for (int j = 0; j < 3; ++j) {
        const int colg = cbase + 48 * wn + 16 * j + lrow;
        if (conv == 0) {
            const float br = b_r[colg];
            #pragma unroll
            for (int r = 0; r < 4; ++r) {
                const int row = n0 + 16 * wm + (lane >> 4) * 4 + r;
                const size_t idx = (size_t)row * 192 + colg;
                const float v  = acc[j][r] + br;
                const float rr = sigmoid_f(v);
                const float m  = bf2f(memH[idx]) + bf2f(memL[idx]);
                unsigned short h, l; splitf(rr * m, h, l);
                rmH[idx] = h; rmL[idx] = l;
            }
        } else {
            const float bg = b_g[colg];
            #pragma unroll
            for (int r = 0; r < 4; ++r) {
                const int row = n0 + 16 * wm + (lane >> 4) * 4 + r;
                const size_t idx = (size_t)row * 192 + colg;
                gate[idx] = sigmoid_f(acc[j][r] + bg);
            }
        }
    }
}

__global__ __launch_bounds__(256, 2)
void k2_c(const unsigned short* __restrict__ rmH, const unsigned short* __restrict__ rmL,
          const unsigned short* __restrict__ WtH, const unsigned short* __restrict__ WtL,
          const float* __restrict__ b_c, const float* __restrict__ gate,
          const unsigned short* __restrict__ memH, const unsigned short* __restrict__ memL,
          unsigned short* __restrict__ memHn, unsigned short* __restrict__ memLn,
          float* __restrict__ outF, int last)
{
    __shared__ __align__(16) unsigned short AH[34 * 192];
    __shared__ __align__(16) unsigned short AL[34 * 192];
    __shared__ __align__(16) unsigned short WB[2][2][96 * 40];

    const int mt = blockIdx.x;          // 0..127
    const int nt = blockIdx.y;          // 0..1
    const int cbase = nt * 96;
    const int n0  = mt * 32;
    const int tid = threadIdx.x;

    #pragma unroll
    for (int it = 0; it < 7; ++it) {
        int q = it * 256 + tid;
        if (q < 34 * 24 * 2) {
            int hl = q >= 34 * 24;
            int qq = hl ? q - 34 * 24 : q;
            int tr = qq / 24;
            int cq = qq - tr * 24;
            int nr = n0 - 1 + tr;
            bool valid = (nr >= 0) && ((nr >> 7) == (n0 >> 7));
            uint4 v = make_uint4(0u, 0u, 0u, 0u);
            if (valid) {
                const unsigned short* src = (hl ? rmL : rmH) + (size_t)nr * 192 + cq * 8;
                v = *reinterpret_cast<const uint4*>(src);
            }
            unsigned int byt = ((unsigned)(cq * 16)) ^ (((unsigned)(tr & 7)) << 4);
            unsigned short* dst = (hl ? AL : AH) + tr * 192 + (byt >> 1);
            *reinterpret_cast<uint4*>(dst) = v;
        }
    }

    const unsigned short* WtHc = WtH + (size_t)(2 * 192 + cbase) * 576;
    const unsigned short* WtLc = WtL + (size_t)(2 * 192 + cbase) * 576;

    auto stageW = [&](int buf, int ch) {
        int k0 = ch * 32;
        #pragma unroll
        for (int it = 0; it < 3; ++it) {
            int q = it * 256 + tid;
            int hl = q >= 96 * 4;
            int qq = hl ? q - 96 * 4 : q;
            int cc = qq >> 2;
            int kq = (qq & 3) * 8;
            const unsigned short* src = (hl ? WtLc : WtHc) + (size_t)cc * 576 + k0 + kq;
            uint4 v = *reinterpret_cast<const uint4*>(src);
            *reinterpret_cast<uint4*>(&WB[buf][hl][cc * 40 + kq]) = v;
        }
    };

    const int lane = tid & 63;
    const int wave = tid >> 6;
    const int wm = wave & 1;
    const int wn = wave >> 1;
    const int lrow = lane & 15;
    const int lk = (lane >> 4) * 8;

    f32x4 acc[3] = { {0.f,0.f,0.f,0.f}, {0.f,0.f,0.f,0.f}, {0.f,0.f,0.f,0.f} };

    stageW(0, 0);
    __syncthreads();

    int buf = 0;
    #pragma unroll
    for (int kk = 0; kk < 3; ++kk) {
        #pragma unroll
        for (int cb = 0; cb < 6; ++cb) {
            const int ch = kk * 6 + cb;
            if (ch < 17) stageW(buf ^ 1, ch + 1);
            const int tr = 16 * wm + lrow + kk;
            const unsigned int abyt = ((unsigned)(cb * 64 + lk * 2)) ^ (((unsigned)(tr & 7)) << 4);
            const int aoff = tr * 192 + (abyt >> 1);
            short8 aH = *reinterpret_cast<const short8*>(&AH[aoff]);
            short8 aL = *reinterpret_cast<const short8*>(&AL[aoff]);
            const int c0 = 48 * wn + lrow;
            short8 bH[3], bL[3];
            #pragma unroll
            for (int j = 0; j < 3; ++j) {
                bH[j] = *reinterpret_cast<const short8*>(&WB[buf][0][(c0 + 16 * j) * 40 + lk]);
                bL[j] = *reinterpret_cast<const short8*>(&WB[buf][1][(c0 + 16 * j) * 40 + lk]);
            }
            #pragma unroll
            for (int j = 0; j < 3; ++j)
                acc[j] = __builtin_amdgcn_mfma_f32_16x16x32_bf16(aH, bH[j], acc[j], 0, 0, 0);
            #pragma unroll
            for (int j = 0; j < 3; ++j)
                acc[j] = __builtin_amdgcn_mfma_f32_16x16x32_bf16(aL, bH[j], acc[j], 0, 0, 0);
            #pragma unroll
            for (int j = 0; j < 3; ++j)
                acc[j] = __builtin_amdgcn_mfma_f32_16x16x32_bf16(aH, bL[j], acc[j], 0, 0, 0);
            __syncthreads();
            buf ^= 1;
        }
    }

    #pragma unroll
    for (int j = 0; j < 3; ++j) {
        const int colg = cbase + 48 * wn + 16 * j + lrow;
        const float bc = b_c[colg];
        #pragma unroll
        for (int r = 0; r < 4; ++r) {
            const int row = n0 + 16 * wm + (lane >> 4) * 4 + r;
            const size_t idx = (size_t)row * 192 + colg;
            const float cand = tanh_f(acc[j][r] + bc);
            const float g = gate[idx];
            float sh = 0.0f;
            if (row & 127) sh = bf2f(memH[idx - 192]) + bf2f(memL[idx - 192]);
            const float o = g * sh + (1.0f - g) * cand;
            if (last) {
                outF[idx] = o;
            } else {
                unsigned short h, l; splitf(o, h, l);
                memHn[idx] = h; memLn[idx] = l;
            }
        }
    }
}

extern "C" void kernel_launch(void* const* d_in, const int* in_sizes, int n_in,
                              void* d_out, int out_size, void* d_ws, size_t ws_size,
                              hipStream_t stream)
{
    (void)in_sizes; (void)n_in; (void)out_size; (void)ws_size;
    const float* x   = (const float*)d_in[0];
    const float* w_r = (const float*)d_in[1];
    const float* b_r = (const float*)d_in[2];
    const float* w_g = (const float*)d_in[3];
    const float* b_g = (const float*)d_in[4];
    const float* w_c = (const float*)d_in[5];
    const float* b_c = (const float*)d_in[6];
    float* out = (float*)d_out;

    const size_t NC = (size_t)NCEL;
    unsigned short* mH[2]; unsigned short* mL[2];
    mH[0] = (unsigned short*)d_ws;
    mL[0] = mH[0] + NC;
    mH[1] = mL[0] + NC;
    mL[1] = mH[1] + NC;
    unsigned short* rmH = mL[1] + NC;
    unsigned short* rmL = rmH + NC;
    float* gate = (float*)(rmL + NC);
    unsigned short* WtH = (unsigned short*)(gate + NC);
    unsigned short* WtL = WtH + (size_t)3 * 192 * 576;

    prep_x<<<dim3((NCEL + 255) / 256), dim3(256), 0, stream>>>(x, mH[0], mL[0]);
    prep_w<<<dim3((3 * 576 * 192 + 255) / 256), dim3(256), 0, stream>>>(w_r, w_g, w_c, WtH, WtL);

    for (int t = 0; t < 128; ++t) {
        const int cur = t & 1;
        const int nxt = cur ^ 1;
        k1_rg<<<dim3(128, 4), dim3(256), 0, stream>>>(
            mH[cur], mL[cur], WtH, WtL, b_r, b_g, gate, rmH, rmL);
        k2_c<<<dim3(128, 2), dim3(256), 0, stream>>>(
            rmH, rmL, WtH, WtL, b_c, gate,
            mH[cur], mL[cur], mH[nxt], mL[nxt], out, t == 127);
    }
}